// Round 3
// baseline (769.310 us; speedup 1.0000x reference)
//
#include <hip/hip_runtime.h>
#include <hip/hip_bf16.h>

// Linear: C[M,N] = A[M,K] @ W[N,K]^T + bias[N].
// HARNESS DTYPES (round-3 correction): reference is float16, which the harness
// maps to FLOAT32 device buffers (fp16 is not in the bf16/float/int mapping).
// Round 1/2 NaNs were fp32 mantissa bits read as bf16 (exp=0xFF w.p. 2^-8).
// Compute: fp32 -> bf16 truncation (v_perm pack) -> mfma_f32_16x16x32_bf16,
// fp32 accumulate, fp32 output + fp32 bias. 2% threshold permits bf16 compute.

typedef unsigned int u32;
typedef __bf16 bf16x8 __attribute__((ext_vector_type(8)));
typedef float f32x4 __attribute__((ext_vector_type(4)));
typedef u32 u32x4 __attribute__((ext_vector_type(4)));

#define M_DIM 8192
#define N_DIM 4096
#define K_DIM 4096
#define BM 128
#define BN 128
#define BK 64

// pack two fp32 -> (bf16(hi)<<16)|bf16(lo) by byte-perm truncation (1 VALU op)
__device__ __forceinline__ u32 pack2bf(float lo, float hi) {
    return __builtin_amdgcn_perm(__float_as_uint(hi), __float_as_uint(lo),
                                 0x07060302u);
}

__global__ __launch_bounds__(256, 2) void linear_f32_bf16mfma_kernel(
    const float* __restrict__ A,     // [M, K] fp32
    const float* __restrict__ W,     // [N, K] fp32
    const float* __restrict__ bias,  // [N]    fp32
    float* __restrict__ C            // [M, N] fp32
) {
    __shared__ __attribute__((aligned(16))) __bf16 sA[BM * BK];
    __shared__ __attribute__((aligned(16))) __bf16 sB[BN * BK];

    const int tid  = threadIdx.x;     // 0..255
    const int lane = tid & 63;
    const int wave = tid >> 6;        // 0..3
    const int quad = lane >> 4;       // 0..3
    const int l16  = lane & 15;
    const int wm   = wave >> 1;       // wave row (2x2 wave grid)
    const int wn   = wave & 1;        // wave col

    const int bn = blockIdx.x;        // N tile (32)
    const int bm = blockIdx.y;        // M tile (64)

    // staging: thread t, iter it covers LDS row (t>>3)+32*it, cols (t&7)*8..+8
    const int srow = tid >> 3;            // 0..31
    const int scol = (tid & 7) * 8;       // element offset in row (of BK=64)

    const float* aBase = A + (size_t)(bm * BM + srow) * K_DIM + scol;
    const float* bBase = W + (size_t)(bn * BN + srow) * K_DIM + scol;

    f32x4 acc[4][4];
#pragma unroll
    for (int i = 0; i < 4; ++i)
#pragma unroll
        for (int j = 0; j < 4; ++j)
            acc[i][j] = f32x4{0.f, 0.f, 0.f, 0.f};

    const int aRow = wm * 64 + l16;   // + mi*16
    const int bRow = wn * 64 + l16;   // + ni*16
    const int kOff = quad * 8;        // A[m=lane&15][k=quad*8+j] fragment layout

    for (int k0 = 0; k0 < K_DIM; k0 += BK) {
        // ---- global fp32 -> registers (8 floats per matrix per it)
        f32x4 ga[4][2], gb[4][2];
#pragma unroll
        for (int it = 0; it < 4; ++it) {
            const float* pa = aBase + (size_t)(it * 32) * K_DIM + k0;
            const float* pb = bBase + (size_t)(it * 32) * K_DIM + k0;
            ga[it][0] = *(const f32x4*)(pa);
            ga[it][1] = *(const f32x4*)(pa + 4);
            gb[it][0] = *(const f32x4*)(pb);
            gb[it][1] = *(const f32x4*)(pb + 4);
        }
        // ---- truncate-pack to bf16 (4 v_perm per 8 floats)
        u32x4 wa[4], wb[4];
#pragma unroll
        for (int it = 0; it < 4; ++it) {
            wa[it] = u32x4{pack2bf(ga[it][0][0], ga[it][0][1]),
                           pack2bf(ga[it][0][2], ga[it][0][3]),
                           pack2bf(ga[it][1][0], ga[it][1][1]),
                           pack2bf(ga[it][1][2], ga[it][1][3])};
            wb[it] = u32x4{pack2bf(gb[it][0][0], gb[it][0][1]),
                           pack2bf(gb[it][0][2], gb[it][0][3]),
                           pack2bf(gb[it][1][0], gb[it][1][1]),
                           pack2bf(gb[it][1][2], gb[it][1][3])};
        }

        __syncthreads();  // prior iteration's LDS reads done before overwrite

        // ---- registers -> LDS (ds_write_b128, linear-in-tid layout)
#pragma unroll
        for (int it = 0; it < 4; ++it) {
            *(u32x4*)&sA[tid * 8 + it * 2048] = wa[it];
            *(u32x4*)&sB[tid * 8 + it * 2048] = wb[it];
        }

        __syncthreads();  // tile visible to all waves

        // ---- compute: 2 k-steps of 32, 16 MFMA each
#pragma unroll
        for (int ks = 0; ks < BK; ks += 32) {
            bf16x8 af[4], bfr[4];
#pragma unroll
            for (int mi = 0; mi < 4; ++mi)
                af[mi] = *(const bf16x8*)&sA[(aRow + mi * 16) * BK + ks + kOff];
#pragma unroll
            for (int ni = 0; ni < 4; ++ni)
                bfr[ni] = *(const bf16x8*)&sB[(bRow + ni * 16) * BK + ks + kOff];
#pragma unroll
            for (int mi = 0; mi < 4; ++mi)
#pragma unroll
                for (int ni = 0; ni < 4; ++ni)
                    acc[mi][ni] = __builtin_amdgcn_mfma_f32_16x16x32_bf16(
                        af[mi], bfr[ni], acc[mi][ni], 0, 0, 0);
        }
    }

    // ---- epilogue: C/D layout col = lane&15, row = quad*4 + reg; fp32 out
    const int colBase = bn * BN + wn * 64 + l16;
    const int rowBase = bm * BM + wm * 64 + quad * 4;
#pragma unroll
    for (int ni = 0; ni < 4; ++ni) {
        const int col = colBase + ni * 16;
        const float bv = bias[col];
#pragma unroll
        for (int mi = 0; mi < 4; ++mi) {
            const int row = rowBase + mi * 16;
#pragma unroll
            for (int r = 0; r < 4; ++r) {
                C[(size_t)(row + r) * N_DIM + col] = acc[mi][ni][r] + bv;
            }
        }
    }
}

extern "C" void kernel_launch(void* const* d_in, const int* in_sizes, int n_in,
                              void* d_out, int out_size, void* d_ws, size_t ws_size,
                              hipStream_t stream) {
    const float* x = (const float*)d_in[0];   // input  [4,2048,4096] -> [8192,4096]
    const float* w = (const float*)d_in[1];   // weight [4096,4096]   (D_OUT, D_IN)
    const float* b = (const float*)d_in[2];   // bias   [4096]
    float* out = (float*)d_out;

    dim3 grid(N_DIM / BN, M_DIM / BM);        // (32, 64) = 2048 blocks
    linear_f32_bf16mfma_kernel<<<grid, 256, 0, stream>>>(x, w, b, out);
}

// Round 4
// 511.833 us; speedup vs baseline: 1.5030x; 1.5030x over previous
//
#include <hip/hip_runtime.h>
#include <hip/hip_bf16.h>

// Linear: C[M,N] = A[M,K] @ W[N,K]^T + bias[N]. fp32 in/out (harness maps fp16
// reference -> fp32 device buffers), bf16 MFMA compute (2% threshold).
//
// Round 4: two-phase.
//  Phase 1 (pack): fp32 -> bf16 truncation into d_ws, TILE-BLOCKED layout
//    (128-row x 64-k tiles contiguous) with XOR chunk swizzle
//    (phys_chunk = logical_chunk ^ (row&7), chunk = 8 elems = 16 B).
//  Phase 2 (GEMM): m97 structure — global_load_lds width=16 from the packed
//    buffer (perfectly linear: lds_linear_offset == packed_linear_offset),
//    swizzled ds_read_b128 (conflict-free, 8-phase floor), 128x128x64 tiles,
//    4 waves x (4x4) mfma_f32_16x16x32_bf16, fp32 epilogue + bias.
// Round-3 kernel kept as fallback when ws_size < 96 MiB.

typedef unsigned short u16;
typedef unsigned int u32;
typedef __bf16 bf16x8 __attribute__((ext_vector_type(8)));
typedef float f32x4 __attribute__((ext_vector_type(4)));
typedef u32 u32x4 __attribute__((ext_vector_type(4)));

#define M_DIM 8192
#define N_DIM 4096
#define K_DIM 4096
#define BM 128
#define BN 128
#define BK 64

#define KT (K_DIM / BK)              // 64 k-tiles
#define A_TILES ((M_DIM / BM) * KT)  // 64*64
#define W_TILES ((N_DIM / BN) * KT)  // 32*64
#define TILE_ELEMS (BM * BK)         // 8192
#define A_CHUNKS (A_TILES * 1024)    // 4,194,304 chunks of 8 elems
#define W_CHUNKS (W_TILES * 1024)    // 2,097,152
#define A_PACK_BYTES ((size_t)A_TILES * TILE_ELEMS * 2)  // 64 MiB
#define W_PACK_BYTES ((size_t)W_TILES * TILE_ELEMS * 2)  // 32 MiB

// pack two fp32 -> (bf16(hi)<<16)|bf16(lo) by byte-perm truncation
__device__ __forceinline__ u32 pack2bf(float lo, float hi) {
    return __builtin_amdgcn_perm(__float_as_uint(hi), __float_as_uint(lo),
                                 0x07060302u);
}

__device__ __forceinline__ void g2l16(const u16* g, __bf16* l) {
    __builtin_amdgcn_global_load_lds((__attribute__((address_space(1))) void*)g,
                                     (__attribute__((address_space(3))) void*)l,
                                     16, 0, 0);
}

// ---------------- Phase 1: convert + tile-pack + swizzle ----------------
// One thread per 16B output chunk. Packed linear offset = gid*8 elements.
// gid -> tile (1024 chunks), slot -> row (slot>>3), phys chunk (slot&7).
// Source chunk = phys ^ (row&7)  (involution).
__global__ __launch_bounds__(256) void pack_bf16_kernel(
    const float* __restrict__ A, const float* __restrict__ W,
    u32x4* __restrict__ aP, u32x4* __restrict__ wP)
{
    int gid = blockIdx.x * 256 + threadIdx.x;
    const float* src;
    u32x4* dst;
    int id;
    if (gid < A_CHUNKS) { src = A; dst = aP; id = gid; }
    else                { src = W; dst = wP; id = gid - A_CHUNKS; }

    const int tile = id >> 10;         // 1024 chunks per tile
    const int slot = id & 1023;
    const int row  = slot >> 3;        // 0..127
    const int cp   = slot & 7;         // physical chunk in packed layout
    const int mt   = tile >> 6;        // row-tile index (tiles are [mt][kt])
    const int kt   = tile & (KT - 1);
    const int sc   = cp ^ (row & 7);   // source (logical) chunk

    const float* p = src + (size_t)(mt * 128 + row) * K_DIM + kt * BK + sc * 8;
    f32x4 v0 = *(const f32x4*)(p);
    f32x4 v1 = *(const f32x4*)(p + 4);
    dst[id] = u32x4{pack2bf(v0[0], v0[1]), pack2bf(v0[2], v0[3]),
                    pack2bf(v1[0], v1[1]), pack2bf(v1[2], v1[3])};
}

// ---------------- Phase 2: GEMM from packed bf16 ----------------
__global__ __launch_bounds__(256, 3) void gemm_packed_kernel(
    const u16* __restrict__ aP,      // packed A tiles
    const u16* __restrict__ wP,      // packed W tiles
    const float* __restrict__ bias,  // [N] fp32
    float* __restrict__ C)           // [M, N] fp32
{
    __shared__ __attribute__((aligned(16))) __bf16 sA[TILE_ELEMS];
    __shared__ __attribute__((aligned(16))) __bf16 sB[TILE_ELEMS];

    const int tid  = threadIdx.x;
    const int lane = tid & 63;
    const int wave = tid >> 6;
    const int quad = lane >> 4;
    const int l16  = lane & 15;
    const int wm   = wave >> 1;
    const int wn   = wave & 1;

    const int bn = blockIdx.x;   // 32 N-tiles
    const int bm = blockIdx.y;   // 64 M-tiles

    const u16* aT = aP + (size_t)bm * KT * TILE_ELEMS + tid * 8;
    const u16* wT = wP + (size_t)bn * KT * TILE_ELEMS + tid * 8;
    __bf16* sAp = &sA[tid * 8];
    __bf16* sBp = &sB[tid * 8];

    f32x4 acc[4][4];
#pragma unroll
    for (int i = 0; i < 4; ++i)
#pragma unroll
        for (int j = 0; j < 4; ++j)
            acc[i][j] = f32x4{0.f, 0.f, 0.f, 0.f};

    const int aRow = wm * 64 + l16;   // + mi*16
    const int bRow = wn * 64 + l16;   // + ni*16
    const int cswz = l16 & 7;         // row&7 (mi*16 / wm*64 keep low 3 bits)

    for (int kt = 0; kt < KT; ++kt) {
        const size_t tb = (size_t)kt * TILE_ELEMS;
#pragma unroll
        for (int it = 0; it < 4; ++it) {
            g2l16(aT + tb + it * 2048, sAp + it * 2048);
            g2l16(wT + tb + it * 2048, sBp + it * 2048);
        }
        __builtin_amdgcn_s_waitcnt(0);   // drain vmcnt before barrier
        __syncthreads();

#pragma unroll
        for (int ks8 = 0; ks8 < 8; ks8 += 4) {      // ks = ks8*8 in {0,32}
            const int cp = (quad + ks8) ^ cswz;      // physical chunk
            bf16x8 af[4], bfr[4];
#pragma unroll
            for (int mi = 0; mi < 4; ++mi)
                af[mi] = *(const bf16x8*)&sA[(aRow + mi * 16) * BK + cp * 8];
#pragma unroll
            for (int ni = 0; ni < 4; ++ni)
                bfr[ni] = *(const bf16x8*)&sB[(bRow + ni * 16) * BK + cp * 8];
#pragma unroll
            for (int mi = 0; mi < 4; ++mi)
#pragma unroll
                for (int ni = 0; ni < 4; ++ni)
                    acc[mi][ni] = __builtin_amdgcn_mfma_f32_16x16x32_bf16(
                        af[mi], bfr[ni], acc[mi][ni], 0, 0, 0);
        }
        __syncthreads();
    }

    // epilogue: C/D layout col = lane&15, row = quad*4 + reg; fp32 out + bias
    const int colBase = bn * BN + wn * 64 + l16;
    const int rowBase = bm * BM + wm * 64 + quad * 4;
#pragma unroll
    for (int ni = 0; ni < 4; ++ni) {
        const int col = colBase + ni * 16;
        const float bv = bias[col];
#pragma unroll
        for (int mi = 0; mi < 4; ++mi) {
            const int row = rowBase + mi * 16;
#pragma unroll
            for (int r = 0; r < 4; ++r)
                C[(size_t)(row + r) * N_DIM + col] = acc[mi][ni][r] + bv;
        }
    }
}

// ---------------- Fallback (round-3 kernel, ws too small) ----------------
__global__ __launch_bounds__(256, 2) void linear_f32_bf16mfma_kernel(
    const float* __restrict__ A, const float* __restrict__ W,
    const float* __restrict__ bias, float* __restrict__ C)
{
    __shared__ __attribute__((aligned(16))) __bf16 sA[BM * BK];
    __shared__ __attribute__((aligned(16))) __bf16 sB[BN * BK];

    const int tid  = threadIdx.x;
    const int lane = tid & 63;
    const int wave = tid >> 6;
    const int quad = lane >> 4;
    const int l16  = lane & 15;
    const int wm   = wave >> 1;
    const int wn   = wave & 1;
    const int bn = blockIdx.x;
    const int bm = blockIdx.y;
    const int srow = tid >> 3;
    const int scol = (tid & 7) * 8;

    const float* aBase = A + (size_t)(bm * BM + srow) * K_DIM + scol;
    const float* bBase = W + (size_t)(bn * BN + srow) * K_DIM + scol;

    f32x4 acc[4][4];
#pragma unroll
    for (int i = 0; i < 4; ++i)
#pragma unroll
        for (int j = 0; j < 4; ++j)
            acc[i][j] = f32x4{0.f, 0.f, 0.f, 0.f};

    const int aRow = wm * 64 + l16;
    const int bRow = wn * 64 + l16;
    const int kOff = quad * 8;

    for (int k0 = 0; k0 < K_DIM; k0 += BK) {
        f32x4 ga[4][2], gb[4][2];
#pragma unroll
        for (int it = 0; it < 4; ++it) {
            const float* pa = aBase + (size_t)(it * 32) * K_DIM + k0;
            const float* pb = bBase + (size_t)(it * 32) * K_DIM + k0;
            ga[it][0] = *(const f32x4*)(pa);
            ga[it][1] = *(const f32x4*)(pa + 4);
            gb[it][0] = *(const f32x4*)(pb);
            gb[it][1] = *(const f32x4*)(pb + 4);
        }
        u32x4 wa[4], wb[4];
#pragma unroll
        for (int it = 0; it < 4; ++it) {
            wa[it] = u32x4{pack2bf(ga[it][0][0], ga[it][0][1]),
                           pack2bf(ga[it][0][2], ga[it][0][3]),
                           pack2bf(ga[it][1][0], ga[it][1][1]),
                           pack2bf(ga[it][1][2], ga[it][1][3])};
            wb[it] = u32x4{pack2bf(gb[it][0][0], gb[it][0][1]),
                           pack2bf(gb[it][0][2], gb[it][0][3]),
                           pack2bf(gb[it][1][0], gb[it][1][1]),
                           pack2bf(gb[it][1][2], gb[it][1][3])};
        }
        __syncthreads();
#pragma unroll
        for (int it = 0; it < 4; ++it) {
            *(u32x4*)&sA[tid * 8 + it * 2048] = wa[it];
            *(u32x4*)&sB[tid * 8 + it * 2048] = wb[it];
        }
        __syncthreads();
#pragma unroll
        for (int ks = 0; ks < BK; ks += 32) {
            bf16x8 af[4], bfr[4];
#pragma unroll
            for (int mi = 0; mi < 4; ++mi)
                af[mi] = *(const bf16x8*)&sA[(aRow + mi * 16) * BK + ks + kOff];
#pragma unroll
            for (int ni = 0; ni < 4; ++ni)
                bfr[ni] = *(const bf16x8*)&sB[(bRow + ni * 16) * BK + ks + kOff];
#pragma unroll
            for (int mi = 0; mi < 4; ++mi)
#pragma unroll
                for (int ni = 0; ni < 4; ++ni)
                    acc[mi][ni] = __builtin_amdgcn_mfma_f32_16x16x32_bf16(
                        af[mi], bfr[ni], acc[mi][ni], 0, 0, 0);
        }
    }
    const int colBase = bn * BN + wn * 64 + l16;
    const int rowBase = bm * BM + wm * 64 + quad * 4;
#pragma unroll
    for (int ni = 0; ni < 4; ++ni) {
        const int col = colBase + ni * 16;
        const float bv = bias[col];
#pragma unroll
        for (int mi = 0; mi < 4; ++mi) {
            const int row = rowBase + mi * 16;
#pragma unroll
            for (int r = 0; r < 4; ++r)
                C[(size_t)(row + r) * N_DIM + col] = acc[mi][ni][r] + bv;
        }
    }
}

extern "C" void kernel_launch(void* const* d_in, const int* in_sizes, int n_in,
                              void* d_out, int out_size, void* d_ws, size_t ws_size,
                              hipStream_t stream) {
    const float* x = (const float*)d_in[0];   // [8192, 4096]
    const float* w = (const float*)d_in[1];   // [4096, 4096]
    const float* b = (const float*)d_in[2];   // [4096]
    float* out = (float*)d_out;

    if (ws_size >= A_PACK_BYTES + W_PACK_BYTES) {
        u32x4* aP = (u32x4*)d_ws;
        u32x4* wP = (u32x4*)((char*)d_ws + A_PACK_BYTES);
        const int total_chunks = A_CHUNKS + W_CHUNKS;
        pack_bf16_kernel<<<total_chunks / 256, 256, 0, stream>>>(x, w, aP, wP);
        dim3 grid(N_DIM / BN, M_DIM / BM);    // (32, 64)
        gemm_packed_kernel<<<grid, 256, 0, stream>>>(
            (const u16*)aP, (const u16*)wP, b, out);
    } else {
        dim3 grid(N_DIM / BN, M_DIM / BM);
        linear_f32_bf16mfma_kernel<<<grid, 256, 0, stream>>>(x, w, b, out);
    }
}